// Round 2
// baseline (276.967 us; speedup 1.0000x reference)
//
#include <hip/hip_runtime.h>
#include <math.h>

// Problem constants
#define M_B   128      // batch
#define N_C   1024     // codes
#define K_D   32000    // feature dim (8*250*16)
#define NTILE 64       // codes per block
#define KCHUNK 640     // K per block (16 N-tiles x 50 K-chunks = 800 blocks)
#define KSTEP 64       // bf16 elems staged in LDS per step (10 steps/block)
#define NSTAGE (KCHUNK / KSTEP)
#define LDSK  (KSTEP + 8)   // +8 bf16 (16B) pad: row stride 144B, 2-way banks (free)
#define TOPK  5
#define TEMP  0.1f

typedef short bf16x8 __attribute__((ext_vector_type(8)));  // 8 bf16 (4 VGPRs)
typedef float f32x4  __attribute__((ext_vector_type(4)));

// ws layout (float offsets)
#define WS_CROSS   0         // [128][1024]
#define WS_CNORM   131072    // [1024]
#define WS_ZERO_N  132096    // floats to zero (cross+cnorm)
#define WS_TOPI    132224    // [128*5] int
#define WS_TOPW    132864    // [128*5]
#define WS_LNORM16 133504    // [128][16] per-(row,block) latent-norm partials

// ---------------------------------------------------------------------------
// fp32x8 -> bf16x8 hi plane + lo plane (exact split: x = hi + lo + ~2^-18 rel)
// ---------------------------------------------------------------------------
__device__ inline void cvt8(const float4 p0, const float4 p1, uint4& hi,
                            uint4& lo) {
  const unsigned int u0 = __float_as_uint(p0.x), u1 = __float_as_uint(p0.y);
  const unsigned int u2 = __float_as_uint(p0.z), u3 = __float_as_uint(p0.w);
  const unsigned int u4 = __float_as_uint(p1.x), u5 = __float_as_uint(p1.y);
  const unsigned int u6 = __float_as_uint(p1.z), u7 = __float_as_uint(p1.w);
  hi.x = (u0 >> 16) | (u1 & 0xFFFF0000u);
  hi.y = (u2 >> 16) | (u3 & 0xFFFF0000u);
  hi.z = (u4 >> 16) | (u5 & 0xFFFF0000u);
  hi.w = (u6 >> 16) | (u7 & 0xFFFF0000u);
  const float l0 = p0.x - __uint_as_float(u0 & 0xFFFF0000u);
  const float l1 = p0.y - __uint_as_float(u1 & 0xFFFF0000u);
  const float l2 = p0.z - __uint_as_float(u2 & 0xFFFF0000u);
  const float l3 = p0.w - __uint_as_float(u3 & 0xFFFF0000u);
  const float l4 = p1.x - __uint_as_float(u4 & 0xFFFF0000u);
  const float l5 = p1.y - __uint_as_float(u5 & 0xFFFF0000u);
  const float l6 = p1.z - __uint_as_float(u6 & 0xFFFF0000u);
  const float l7 = p1.w - __uint_as_float(u7 & 0xFFFF0000u);
  lo.x = (__float_as_uint(l0) >> 16) | (__float_as_uint(l1) & 0xFFFF0000u);
  lo.y = (__float_as_uint(l2) >> 16) | (__float_as_uint(l3) & 0xFFFF0000u);
  lo.z = (__float_as_uint(l4) >> 16) | (__float_as_uint(l5) & 0xFFFF0000u);
  lo.w = (__float_as_uint(l6) >> 16) | (__float_as_uint(l7) & 0xFFFF0000u);
}

__device__ inline float sq8(const float4 p0, const float4 p1) {
  return p0.x * p0.x + p0.y * p0.y + p0.z * p0.z + p0.w * p0.w +
         p1.x * p1.x + p1.y * p1.y + p1.z * p1.z + p1.w * p1.w;
}

// ---------------------------------------------------------------------------
// prep (merged): bx<16  -> convert latent row `by` into Ah/Al bf16 planes
//                         (stored in out's quant region — dead until quantize
//                         overwrites it) + lnorm16 partials (no atomics).
//                bx==16 -> zero cross/cnorm + copy usage.
// ---------------------------------------------------------------------------
__global__ __launch_bounds__(256) void prep(
    const float* __restrict__ latent, const float* __restrict__ usage_in,
    float* __restrict__ ws, float* __restrict__ usage_out,
    unsigned short* __restrict__ aplanes) {
  const int tid = threadIdx.x;
  const int bx = blockIdx.x;
  const int by = blockIdx.y;  // latent row 0..127
  if (bx == 16) {             // chores
    const int id2 = by * 256 + tid;
#pragma unroll
    for (int j = 0; j < 5; ++j) {
      const int idx = id2 + j * 32768;
      if (idx < WS_ZERO_N) ws[idx] = 0.f;
    }
    if (id2 < N_C) usage_out[id2] = usage_in[id2];
    return;
  }
  // ---- cvt: 4000 units of 8 floats per row; block bx covers 256 units ----
  const int u = bx * 256 + tid;
  float lsq = 0.f;
  if (u < 4000) {
    const int k = u * 8;
    const float* src = latent + (size_t)by * K_D + k;
    const float4 p0 = *reinterpret_cast<const float4*>(src);
    const float4 p1 = *reinterpret_cast<const float4*>(src + 4);
    uint4 hi, lo;
    cvt8(p0, p1, hi, lo);
    unsigned short* ah = aplanes + (size_t)by * K_D + k;
    *reinterpret_cast<uint4*>(ah) = hi;
    *reinterpret_cast<uint4*>(ah + (size_t)M_B * K_D) = lo;
    lsq = sq8(p0, p1);
  }
  // wave reduce (all lanes same row; inactive lanes carry 0)
  lsq += __shfl_down(lsq, 32);
  lsq += __shfl_down(lsq, 16);
  lsq += __shfl_down(lsq, 8);
  lsq += __shfl_down(lsq, 4);
  lsq += __shfl_down(lsq, 2);
  lsq += __shfl_down(lsq, 1);
  __shared__ float wpart[4];
  if ((tid & 63) == 0) wpart[tid >> 6] = lsq;
  __syncthreads();
  if (tid == 0)
    (ws + WS_LNORM16)[by * 16 + bx] =
        wpart[0] + wpart[1] + wpart[2] + wpart[3];
}

// ---------------------------------------------------------------------------
// Split-bf16 MFMA distance GEMM v3.
//  - A fragments load directly as precomputed bf16 planes (no in-loop cvt).
//  - Pipeline that survives __syncthreads' vmcnt(0) drain: ALL loads are
//    issued immediately AFTER the barrier and consumed ≥1 full step later,
//    so each barrier only drains step-old (mostly retired) loads:
//      barrier -> issue A(s), issue B(s+2) -> MFMA on LDS[cur]
//              -> cvt+write B(s+1) (loaded last iter, retired) -> swap
//  - 10 steps/block amortize prologue/epilogue; 26 MB atomic traffic.
// ---------------------------------------------------------------------------
__global__ __launch_bounds__(256, 3) void gemm_dist(
    const unsigned short* __restrict__ aplanes,
    const float* __restrict__ codebook, float* __restrict__ cross,
    float* __restrict__ cnorm) {
  __shared__ alignas(16) unsigned short Bh[2][NTILE][LDSK];
  __shared__ alignas(16) unsigned short Bl[2][NTILE][LDSK];

  const int tid  = threadIdx.x;
  const int nt   = blockIdx.x;   // 0..15 N tile
  const int kc   = blockIdx.y;   // 0..49 K chunk
  const int wave = tid >> 6;     // 0..3: M rows [32w, 32w+32)
  const int lane = tid & 63;
  const int lrow = lane & 15;    // MFMA fragment row/col index
  const int quad = lane >> 4;    // MFMA k-quad

  const int brow = tid >> 2;        // staging: B row 0..63
  const int bcol = (tid & 3) * 16;  // 16 k-elems (2 float4) per thread

  f32x4 acc[2][4];
#pragma unroll
  for (int mt = 0; mt < 2; ++mt)
#pragma unroll
    for (int n = 0; n < 4; ++n) {
      acc[mt][n][0] = 0.f; acc[mt][n][1] = 0.f;
      acc[mt][n][2] = 0.f; acc[mt][n][3] = 0.f;
    }
  float csq = 0.f;

  const int kbase = kc * KCHUNK;
  const float* browp = codebook + (size_t)(nt * NTILE + brow) * K_D;
  const unsigned short* al_base = aplanes + (size_t)M_B * K_D;

  // ---- prologue: stage step 0 into buffer 0 (one-time exposed latency) ----
#pragma unroll
  for (int u = 0; u < 2; ++u) {
    const int kk = kbase + bcol + u * 8;
    const float4 p0 = *reinterpret_cast<const float4*>(browp + kk);
    const float4 p1 = *reinterpret_cast<const float4*>(browp + kk + 4);
    uint4 hi, lo;
    cvt8(p0, p1, hi, lo);
    *reinterpret_cast<uint4*>(&Bh[0][brow][bcol + u * 8]) = hi;
    *reinterpret_cast<uint4*>(&Bl[0][brow][bcol + u * 8]) = lo;
    csq += sq8(p0, p1);
  }
  // ---- preload B(1) into regs ----
  float4 bp[2][2];
  {
    const int kn = kbase + KSTEP + bcol;
#pragma unroll
    for (int u = 0; u < 2; ++u) {
      bp[u][0] = *reinterpret_cast<const float4*>(browp + kn + u * 8);
      bp[u][1] = *reinterpret_cast<const float4*>(browp + kn + u * 8 + 4);
    }
  }

  int cur = 0;
  for (int s = 0; s < NSTAGE; ++s) {
    __syncthreads();  // buf[cur] ready; drains only step-old loads (cheap)
    const int k0 = kbase + s * KSTEP;
    // ---- issue A(s) fragment loads (bf16 planes, L3-hot) ----
    bf16x8 ah[2][2], al[2][2];
#pragma unroll
    for (int mt = 0; mt < 2; ++mt) {
      const size_t ro =
          (size_t)(wave * 32 + mt * 16 + lrow) * K_D + k0 + quad * 8;
#pragma unroll
      for (int kh = 0; kh < 2; ++kh) {
        ah[mt][kh] =
            *reinterpret_cast<const bf16x8*>(aplanes + ro + kh * 32);
        al[mt][kh] =
            *reinterpret_cast<const bf16x8*>(al_base + ro + kh * 32);
      }
    }
    // ---- issue B(s+2) loads (consumed bottom of NEXT iter) ----
    float4 bq[2][2];
    if (s + 2 < NSTAGE) {
      const int kn = kbase + (s + 2) * KSTEP + bcol;
#pragma unroll
      for (int u = 0; u < 2; ++u) {
        bq[u][0] = *reinterpret_cast<const float4*>(browp + kn + u * 8);
        bq[u][1] = *reinterpret_cast<const float4*>(browp + kn + u * 8 + 4);
      }
    }
    // ---- MFMA on buf[cur] ----
#pragma unroll
    for (int kh = 0; kh < 2; ++kh) {
      const int kf = kh * 32 + quad * 8;
#pragma unroll
      for (int n = 0; n < 4; ++n) {
        const bf16x8 bh =
            *reinterpret_cast<const bf16x8*>(&Bh[cur][n * 16 + lrow][kf]);
        const bf16x8 bl =
            *reinterpret_cast<const bf16x8*>(&Bl[cur][n * 16 + lrow][kf]);
#pragma unroll
        for (int mt = 0; mt < 2; ++mt) {
          acc[mt][n] = __builtin_amdgcn_mfma_f32_16x16x32_bf16(
              ah[mt][kh], bh, acc[mt][n], 0, 0, 0);
          acc[mt][n] = __builtin_amdgcn_mfma_f32_16x16x32_bf16(
              ah[mt][kh], bl, acc[mt][n], 0, 0, 0);
          acc[mt][n] = __builtin_amdgcn_mfma_f32_16x16x32_bf16(
              al[mt][kh], bh, acc[mt][n], 0, 0, 0);
        }
      }
    }
    // ---- cvt + write B(s+1) (loaded last iter -> already retired) ----
    if (s + 1 < NSTAGE) {
      const int nxt = cur ^ 1;
#pragma unroll
      for (int u = 0; u < 2; ++u) {
        uint4 hi, lo;
        cvt8(bp[u][0], bp[u][1], hi, lo);
        *reinterpret_cast<uint4*>(&Bh[nxt][brow][bcol + u * 8]) = hi;
        *reinterpret_cast<uint4*>(&Bl[nxt][brow][bcol + u * 8]) = lo;
        csq += sq8(bp[u][0], bp[u][1]);
      }
    }
    if (s + 2 < NSTAGE) {
#pragma unroll
      for (int u = 0; u < 2; ++u) {
        bp[u][0] = bq[u][0];
        bp[u][1] = bq[u][1];
      }
    }
    cur ^= 1;
  }

  // ---- split-K accumulate: C/D layout col=lane&15, row=quad*4+reg (m89) ----
#pragma unroll
  for (int mt = 0; mt < 2; ++mt) {
    const int mrow0 = wave * 32 + mt * 16 + quad * 4;
#pragma unroll
    for (int n = 0; n < 4; ++n) {
      const int col = nt * NTILE + n * 16 + lrow;
#pragma unroll
      for (int r = 0; r < 4; ++r)
        atomicAdd(cross + (size_t)(mrow0 + r) * N_C + col, acc[mt][n][r]);
    }
  }

  // ---- codebook norms: 4 threads (tid&3) share row brow ----
  csq += __shfl_down(csq, 2, 4);
  csq += __shfl_down(csq, 1, 4);
  if ((tid & 3) == 0) atomicAdd(cnorm + nt * NTILE + brow, csq);
}

// ---------------------------------------------------------------------------
// Per-latent finalize: d2 -> top-5 (lowest-index tie-break) -> softmax ->
// outputs + usage scatter + ws stash for the quantize gather.
// ---------------------------------------------------------------------------
__global__ __launch_bounds__(256) void finalize(
    const float* __restrict__ cross, const float* __restrict__ cnorm,
    const float* __restrict__ lnorm16, float* __restrict__ out_idx,
    float* __restrict__ out_dist, float* __restrict__ out_usage,
    int* __restrict__ topidx, float* __restrict__ topw) {
  const int b = blockIdx.x;
  const int tid = threadIdx.x;
  __shared__ float rv[256];
  __shared__ int ri[256];
  __shared__ float seld[TOPK];
  __shared__ int selj[TOPK];

  float ln = 0.f;
#pragma unroll
  for (int x = 0; x < 16; ++x) ln += lnorm16[b * 16 + x];

  float d[4];
  bool used[4];
#pragma unroll
  for (int i = 0; i < 4; i++) {
    const int j = i * 256 + tid;
    d[i] = ln + cnorm[j] - 2.f * cross[b * N_C + j];
    used[i] = false;
  }
  for (int it = 0; it < TOPK; ++it) {
    float best = 3.4e38f;
    int bj = N_C;
#pragma unroll
    for (int i = 0; i < 4; i++) {  // ascending j + strict < => lowest idx wins
      const int j = i * 256 + tid;
      if (!used[i] && d[i] < best) { best = d[i]; bj = j; }
    }
    rv[tid] = best;
    ri[tid] = bj;
    __syncthreads();
    for (int off = 128; off > 0; off >>= 1) {
      if (tid < off) {
        const float ov = rv[tid + off];
        const int oj = ri[tid + off];
        if (ov < rv[tid] || (ov == rv[tid] && oj < ri[tid])) {
          rv[tid] = ov;
          ri[tid] = oj;
        }
      }
      __syncthreads();
    }
    const int jw = ri[0];
    const float dw = rv[0];
    if (tid == 0) { selj[it] = jw; seld[it] = dw; }
    if ((jw & 255) == tid) used[jw >> 8] = true;  // exclude winner
    __syncthreads();
  }
  if (tid == 0) {
    float dist[TOPK], w[TOPK], wsum = 0.f;
#pragma unroll
    for (int k = 0; k < TOPK; k++) dist[k] = sqrtf(fmaxf(seld[k], 0.f));
#pragma unroll
    for (int k = 0; k < TOPK; k++) {
      w[k] = expf((dist[0] - dist[k]) / TEMP);  // stable: dist[0] is min
      wsum += w[k];
    }
#pragma unroll
    for (int k = 0; k < TOPK; k++) {
      w[k] /= wsum;
      topidx[b * TOPK + k] = selj[k];
      topw[b * TOPK + k] = w[k];
      atomicAdd(out_usage + selj[k], w[k]);
    }
    out_idx[b] = (float)selj[0];  // harness reads flat float32 buffer
    out_dist[b] = dist[0];
  }
}

// ---------------------------------------------------------------------------
// quantized[b,:] = sum_k w[b,k] * codebook[idx[b,k],:]   (float4 gather)
// NOTE: overwrites the quant region that prep used as A-plane scratch.
// ---------------------------------------------------------------------------
__global__ __launch_bounds__(256) void quantize(
    const float* __restrict__ codebook, const int* __restrict__ topidx,
    const float* __restrict__ topw, float* __restrict__ out) {
  const int b = blockIdx.y;
  const int dc = blockIdx.x;  // 8 chunks of 1000 float4 = 32000 floats
  const int tid = threadIdx.x;
  int idx[TOPK];
  float w[TOPK];
#pragma unroll
  for (int k = 0; k < TOPK; k++) {
    idx[k] = topidx[b * TOPK + k];
    w[k] = topw[b * TOPK + k];
  }
  const int f4base = dc * 1000;
#pragma unroll
  for (int s = 0; s < 4; s++) {
    const int f = tid + s * 256;
    if (f < 1000) {
      const int dpos = (f4base + f) * 4;
      float4 q = {0.f, 0.f, 0.f, 0.f};
#pragma unroll
      for (int k = 0; k < TOPK; k++) {
        const float4 c = *reinterpret_cast<const float4*>(
            codebook + (size_t)idx[k] * K_D + dpos);
        q.x += w[k] * c.x;
        q.y += w[k] * c.y;
        q.z += w[k] * c.z;
        q.w += w[k] * c.w;
      }
      *reinterpret_cast<float4*>(out + (size_t)b * K_D + dpos) = q;
    }
  }
}

// ---------------------------------------------------------------------------
extern "C" void kernel_launch(void* const* d_in, const int* in_sizes, int n_in,
                              void* d_out, int out_size, void* d_ws,
                              size_t ws_size, hipStream_t stream) {
  const float* latent = (const float*)d_in[0];    // 128*32000
  const float* codebook = (const float*)d_in[1];  // 1024*32000
  const float* usage_in = (const float*)d_in[2];  // 1024

  float* out = (float*)d_out;
  float* quant = out;                // 4,096,000 floats
  float* out_idx = out + 4096000;    // 128
  float* out_dist = out + 4096128;   // 128
  float* out_usage = out + 4096256;  // 1024

  float* ws = (float*)d_ws;
  float* cross = ws + WS_CROSS;
  float* cnorm = ws + WS_CNORM;
  float* lnorm16 = ws + WS_LNORM16;
  int* topidx = (int*)(ws + WS_TOPI);
  float* topw = ws + WS_TOPW;

  // A-plane scratch: quant region is exactly 16,384,000 B = Ah+Al planes,
  // dead until quantize fully overwrites it.
  unsigned short* aplanes = (unsigned short*)quant;

  prep<<<dim3(17, 128), 256, 0, stream>>>(latent, usage_in, ws, out_usage,
                                          aplanes);
  gemm_dist<<<dim3(16, 50), 256, 0, stream>>>(aplanes, codebook, cross, cnorm);
  finalize<<<128, 256, 0, stream>>>(cross, cnorm, lnorm16, out_idx, out_dist,
                                    out_usage, topidx, topw);
  quantize<<<dim3(8, 128), 256, 0, stream>>>(codebook, topidx, topw, quant);
}